// Round 2
// baseline (1740.449 us; speedup 1.0000x reference)
//
#include <hip/hip_runtime.h>
#include <math.h>

#define NB 4
#define NN 4096
#define KSEL 204
#define QKSCALE 0.31622776601683794f

// workspace layout in floats
#define WS_Q 0
#define WS_K (NB * NN * 10)        // 163840
#define WS_V (2 * NB * NN * 10)    // 327680
#define WS_LG (3 * NB * NN * 10)   // 491520  (+ NB*NN*2 = 32768)

#define SEQ_PER_BLOCK 16

__global__ __launch_bounds__(256) void featqkv_kernel(
    const float* __restrict__ x,
    const float* __restrict__ w2, const float* __restrict__ b2,
    const float* __restrict__ w3, const float* __restrict__ b3,
    const float* __restrict__ w4, const float* __restrict__ b4,
    const float* __restrict__ w5, const float* __restrict__ b5,
    const float* __restrict__ w6, const float* __restrict__ b6,
    const float* __restrict__ w7, const float* __restrict__ b7,
    const float* __restrict__ wq, const float* __restrict__ bq,
    const float* __restrict__ wk, const float* __restrict__ bk,
    const float* __restrict__ wv, const float* __restrict__ bv,
    float* __restrict__ q_out, float* __restrict__ k_out, float* __restrict__ v_out)
{
    __shared__ float xs[SEQ_PER_BLOCK * 360];
    __shared__ float wconv[840];
    __shared__ float bconv[14];
    __shared__ float wqkv[420];
    __shared__ float bqkv[30];
    __shared__ float feats[SEQ_PER_BLOCK * 14];

    const int t = threadIdx.x;
    const int g0 = blockIdx.x * SEQ_PER_BLOCK;

    const float* xg = x + (size_t)g0 * 360;
    for (int i = t; i < SEQ_PER_BLOCK * 360; i += 256) xs[i] = xg[i];
    for (int i = t; i < 90; i += 256) wconv[i] = w2[i];
    for (int i = t; i < 135; i += 256) wconv[90 + i] = w3[i];
    for (int i = t; i < 180; i += 256) wconv[225 + i] = w4[i];
    for (int i = t; i < 150; i += 256) wconv[405 + i] = w5[i];
    for (int i = t; i < 180; i += 256) wconv[555 + i] = w6[i];
    for (int i = t; i < 105; i += 256) wconv[735 + i] = w7[i];
    if (t < 3) bconv[t] = b2[t];
    else if (t < 6) bconv[t] = b3[t - 3];
    else if (t < 9) bconv[t] = b4[t - 6];
    else if (t < 11) bconv[t] = b5[t - 9];
    else if (t < 13) bconv[t] = b6[t - 11];
    else if (t == 13) bconv[t] = b7[0];
    for (int i = t; i < 140; i += 256) wqkv[i] = wq[i];
    for (int i = t; i < 140; i += 256) wqkv[140 + i] = wk[i];
    for (int i = t; i < 140; i += 256) wqkv[280 + i] = wv[i];
    if (t < 10) bqkv[t] = bq[t];
    else if (t < 20) bqkv[t] = bk[t - 10];
    else if (t < 30) bqkv[t] = bv[t - 20];
    __syncthreads();

    const int seq = t >> 4;
    const int wkr = t & 15;

    if (wkr < 14) {
        const int ch = wkr;
        int h, fi, woff;
        if (ch < 3)       { h = 2; fi = ch;      woff = 0   + fi * 30; }
        else if (ch < 6)  { h = 3; fi = ch - 3;  woff = 90  + fi * 45; }
        else if (ch < 9)  { h = 4; fi = ch - 6;  woff = 225 + fi * 60; }
        else if (ch < 11) { h = 5; fi = ch - 9;  woff = 405 + fi * 75; }
        else if (ch < 13) { h = 6; fi = ch - 11; woff = 555 + fi * 90; }
        else              { h = 7; fi = 0;       woff = 735; }
        const int T = 24 - h + 1;

        float acc[23];
#pragma unroll
        for (int i2 = 0; i2 < 23; i2++) acc[i2] = 0.f;
        const float* xrow = &xs[seq * 360];
        for (int c = 0; c < 15; c++) {
            float xr[24];
#pragma unroll
            for (int u = 0; u < 24; u++) xr[u] = xrow[c * 24 + u];
#pragma unroll
            for (int j = 0; j < 7; j++) {
                if (j < h) {
                    float wv_ = wconv[woff + c * h + j];
#pragma unroll
                    for (int tt = 0; tt < 23; tt++) {
                        if (tt < T) acc[tt] = fmaf(xr[tt + j], wv_, acc[tt]);
                    }
                }
            }
        }
        float m = -1e30f;
#pragma unroll
        for (int tt = 0; tt < 23; tt++) {
            if (tt < T) m = fmaxf(m, acc[tt]);
        }
        feats[seq * 14 + ch] = fmaxf(m + bconv[ch], 0.f);
    }
    __syncthreads();

    const int g = g0 + seq;
    for (int o = wkr; o < 30; o += 16) {
        const int type = o / 10;
        const int comp = o % 10;
        const float* wrow = &wqkv[type * 140 + comp * 14];
        const float* frow = &feats[seq * 14];
        float a = bqkv[type * 10 + comp];
#pragma unroll
        for (int ii = 0; ii < 14; ii++) a = fmaf(frow[ii], wrow[ii], a);
        if (type == 0) q_out[(size_t)g * 10 + comp] = a;
        else if (type == 1) k_out[(size_t)g * 10 + comp] = a;
        else v_out[(size_t)g * 10 + comp] = a;
    }
}

__device__ __forceinline__ float dec_key(unsigned int k) {
    return (k & 0x80000000u) ? __uint_as_float(k ^ 0x80000000u)
                             : __uint_as_float(~k);
}

// One wave (64 threads) per query row. Scores live in registers (64 keys/lane).
__global__ __launch_bounds__(64, 4) void attn_kernel(
    const float* __restrict__ qbuf, const float* __restrict__ kbuf,
    const float* __restrict__ vbuf,
    const float* __restrict__ w_attn, const float* __restrict__ b_attn,
    const float* __restrict__ w_mil, const float* __restrict__ b_mil,
    float* __restrict__ out_probs, float* __restrict__ logits)
{
    __shared__ unsigned int hist[256];
    __shared__ unsigned long long surv[256];
    __shared__ unsigned long long sh_pfx;
    __shared__ unsigned int sh_kept;
    __shared__ int sh_done;
    __shared__ unsigned int cnt;
    __shared__ float attn_sh[14];

    const int t = threadIdx.x;
    const int row = blockIdx.x;
    const int b_ = row >> 12;

    // ---- P1: scores -> monotonic 32-bit keys in registers ----
    float q[10];
#pragma unroll
    for (int c = 0; c < 10; c++) q[c] = qbuf[(size_t)row * 10 + c];

    const float* kb = kbuf + (size_t)b_ * NN * 10;
    unsigned int k32[64];
#pragma unroll
    for (int i = 0; i < 64; i++) {
        const float* kr = kb + (size_t)(i * 64 + t) * 10;
        float a = 0.f;
#pragma unroll
        for (int c = 0; c < 10; c++) a = fmaf(q[c], kr[c], a);
        unsigned int u = __float_as_uint(a);
        k32[i] = (u & 0x80000000u) ? ~u : (u | 0x80000000u);
    }

    // ---- P2: radix select 204th-largest composite (key32<<16 | (4095-j)) ----
    unsigned long long pfx = 0ULL;
    unsigned int kept = KSEL;
    if (t == 0) sh_done = 0;
    __syncthreads();

#pragma unroll 1
    for (int pass = 0; pass < 6; pass++) {
        if (pass >= 4 && sh_done) break;   // score bits resolved uniquely
        const int shift = 40 - 8 * pass;
#pragma unroll
        for (int i = t; i < 256; i += 64) hist[i] = 0u;
        __syncthreads();
#pragma unroll
        for (int i = 0; i < 64; i++) {
            unsigned long long key = (((unsigned long long)k32[i]) << 16)
                                   | (unsigned long long)(4095 - (i * 64 + t));
            if ((key >> (shift + 8)) == (pfx >> (shift + 8))) {
                atomicAdd(&hist[(unsigned int)(key >> shift) & 255u], 1u);
            }
        }
        __syncthreads();
        // single-wave suffix scan over 256 bins (4 bins/lane) + pivot select
        unsigned int h0 = hist[4 * t], h1 = hist[4 * t + 1];
        unsigned int h2 = hist[4 * t + 2], h3 = hist[4 * t + 3];
        unsigned int s3 = h3, s2 = h2 + s3, s1 = h1 + s2, s0 = h0 + s1;
        unsigned int acc = s0;
#pragma unroll
        for (int off = 1; off < 64; off <<= 1) {
            unsigned int o = __shfl_down(acc, off);
            if (t + off < 64) acc += o;
        }
        const unsigned int tail = acc - s0;
        unsigned int suf0 = s0 + tail, suf1 = s1 + tail, suf2 = s2 + tail, suf3 = s3 + tail;
        unsigned int sfn0 = suf1, sfn1 = suf2, sfn2 = suf3, sfn3 = tail;
#pragma unroll
        for (int kk = 0; kk < 4; kk++) {
            unsigned int suf = (kk == 0) ? suf0 : (kk == 1) ? suf1 : (kk == 2) ? suf2 : suf3;
            unsigned int sfn = (kk == 0) ? sfn0 : (kk == 1) ? sfn1 : (kk == 2) ? sfn2 : sfn3;
            if (suf >= kept && sfn < kept) {
                sh_pfx = pfx | (((unsigned long long)(4 * t + kk)) << shift);
                unsigned int kn = kept - sfn;
                sh_kept = kn;
                if (pass == 3) sh_done = ((suf - sfn) == kn) ? 1 : 0;
            }
        }
        __syncthreads();
        pfx = sh_pfx;
        kept = sh_kept;
        __syncthreads();
    }

    // ---- P3: compact survivors (exactly KSEL by construction) ----
    if (t == 0) cnt = 0u;
#pragma unroll
    for (int i = t; i < 256; i += 64) surv[i] = 0ULL;
    __syncthreads();
#pragma unroll
    for (int i = 0; i < 64; i++) {
        unsigned long long key = (((unsigned long long)k32[i]) << 16)
                               | (unsigned long long)(4095 - (i * 64 + t));
        if (key >= pfx) {
            unsigned int p = atomicAdd(&cnt, 1u);
            surv[p] = key;
        }
    }
    __syncthreads();

    // ---- P4: bitonic sort 256 keys descending (2 pairs/lane/step) ----
#pragma unroll 1
    for (int k2 = 2; k2 <= 256; k2 <<= 1) {
#pragma unroll 1
        for (int j2 = k2 >> 1; j2 > 0; j2 >>= 1) {
#pragma unroll
            for (int pp = 0; pp < 2; pp++) {
                int p2 = t + pp * 64;
                int i = ((p2 & ~(j2 - 1)) << 1) | (p2 & (j2 - 1));
                int ip = i | j2;
                unsigned long long a = surv[i], bkey = surv[ip];
                bool desc = ((i & k2) == 0);
                if (desc ? (a < bkey) : (a > bkey)) { surv[i] = bkey; surv[ip] = a; }
            }
            __syncthreads();
        }
    }

    // ---- P5: softmax over selected scores (sorted order) ----
    const float smax = dec_key((unsigned int)(surv[0] >> 16)) * QKSCALE;
    float pv0, pv1, pv2, pv3;
    int jj0, jj1, jj2, jj3;
    float dsum = 0.f;
    {
        unsigned long long key;
        key = surv[t];
        jj0 = 4095 - (int)(key & 0xFFFFu);
        pv0 = expf(dec_key((unsigned int)(key >> 16)) * QKSCALE - smax);
        key = surv[t + 64];
        jj1 = 4095 - (int)(key & 0xFFFFu);
        pv1 = expf(dec_key((unsigned int)(key >> 16)) * QKSCALE - smax);
        key = surv[t + 128];
        jj2 = 4095 - (int)(key & 0xFFFFu);
        pv2 = expf(dec_key((unsigned int)(key >> 16)) * QKSCALE - smax);
        key = surv[t + 192];
        jj3 = 4095 - (int)(key & 0xFFFFu);
        pv3 = (t + 192 < KSEL) ? expf(dec_key((unsigned int)(key >> 16)) * QKSCALE - smax) : 0.f;
        dsum = pv0 + pv1 + pv2 + pv3;
    }
#pragma unroll
    for (int off = 32; off > 0; off >>= 1) dsum += __shfl_xor(dsum, off);
    const float inv = 1.f / dsum;

    // ---- P6: probs out + ctx = sum p*v ----
    float ctx[10];
#pragma unroll
    for (int d = 0; d < 10; d++) ctx[d] = 0.f;
    const float* vb = vbuf + (size_t)b_ * NN * 10;
    float* po = out_probs + (size_t)row * KSEL;
    {
        float pn;
        const float* vr;
        pn = pv0 * inv; po[t] = pn; vr = vb + (size_t)jj0 * 10;
#pragma unroll
        for (int d = 0; d < 10; d++) ctx[d] = fmaf(pn, vr[d], ctx[d]);
        pn = pv1 * inv; po[t + 64] = pn; vr = vb + (size_t)jj1 * 10;
#pragma unroll
        for (int d = 0; d < 10; d++) ctx[d] = fmaf(pn, vr[d], ctx[d]);
        pn = pv2 * inv; po[t + 128] = pn; vr = vb + (size_t)jj2 * 10;
#pragma unroll
        for (int d = 0; d < 10; d++) ctx[d] = fmaf(pn, vr[d], ctx[d]);
        if (t + 192 < KSEL) {
            pn = pv3 * inv; po[t + 192] = pn; vr = vb + (size_t)jj3 * 10;
#pragma unroll
            for (int d = 0; d < 10; d++) ctx[d] = fmaf(pn, vr[d], ctx[d]);
        }
    }
#pragma unroll
    for (int d = 0; d < 10; d++) {
#pragma unroll
        for (int off = 32; off > 0; off >>= 1) ctx[d] += __shfl_xor(ctx[d], off);
    }

    // ---- P7: attn projection + mil logits ----
    if (t < 14) {
        float a = b_attn[t];
#pragma unroll
        for (int d = 0; d < 10; d++) a = fmaf(ctx[d], w_attn[t * 10 + d], a);
        attn_sh[t] = a;
    }
    __syncthreads();
    if (t < 2) {
        float lg = b_mil[t];
#pragma unroll
        for (int ii = 0; ii < 14; ii++) lg = fmaf(attn_sh[ii], w_mil[t * 14 + ii], lg);
        logits[(size_t)row * 2 + t] = lg;
    }
}

__global__ __launch_bounds__(256) void pool_kernel(
    const float* __restrict__ logits, float* __restrict__ out)
{
    __shared__ float red[256];
    const int t = threadIdx.x;
    const int bc = blockIdx.x;
    const int b_ = bc >> 1;
    const int c_ = bc & 1;
    float a = 0.f;
    for (int n2 = t; n2 < NN; n2 += 256)
        a += logits[((size_t)b_ * NN + n2) * 2 + c_];
    red[t] = a;
    __syncthreads();
    for (int off = 128; off > 0; off >>= 1) {
        if (t < off) red[t] += red[t + off];
        __syncthreads();
    }
    if (t == 0) out[bc] = red[0] * (1.f / 4096.f);
}

extern "C" void kernel_launch(void* const* d_in, const int* in_sizes, int n_in,
                              void* d_out, int out_size, void* d_ws, size_t ws_size,
                              hipStream_t stream) {
    const float* x  = (const float*)d_in[0];
    const float* w2 = (const float*)d_in[1];  const float* b2 = (const float*)d_in[2];
    const float* w3 = (const float*)d_in[3];  const float* b3 = (const float*)d_in[4];
    const float* w4 = (const float*)d_in[5];  const float* b4 = (const float*)d_in[6];
    const float* w5 = (const float*)d_in[7];  const float* b5 = (const float*)d_in[8];
    const float* w6 = (const float*)d_in[9];  const float* b6 = (const float*)d_in[10];
    const float* w7 = (const float*)d_in[11]; const float* b7 = (const float*)d_in[12];
    const float* wq = (const float*)d_in[13]; const float* bq = (const float*)d_in[14];
    const float* wk = (const float*)d_in[15]; const float* bk = (const float*)d_in[16];
    const float* wv = (const float*)d_in[17]; const float* bv = (const float*)d_in[18];
    const float* wat = (const float*)d_in[19]; const float* bat = (const float*)d_in[20];
    const float* wm = (const float*)d_in[21];  const float* bm = (const float*)d_in[22];

    float* ws = (float*)d_ws;
    float* qb = ws + WS_Q;
    float* kbf = ws + WS_K;
    float* vb = ws + WS_V;
    float* lg = ws + WS_LG;
    float* out = (float*)d_out;

    hipLaunchKernelGGL(featqkv_kernel, dim3(NB * NN / SEQ_PER_BLOCK), dim3(256), 0, stream,
                       x, w2, b2, w3, b3, w4, b4, w5, b5, w6, b6, w7, b7,
                       wq, bq, wk, bk, wv, bv, qb, kbf, vb);
    hipLaunchKernelGGL(attn_kernel, dim3(NB * NN), dim3(64), 0, stream,
                       qb, kbf, vb, wat, bat, wm, bm, out + 8, lg);
    hipLaunchKernelGGL(pool_kernel, dim3(8), dim3(256), 0, stream, lg, out);
}

// Round 3
// 537.862 us; speedup vs baseline: 3.2359x; 3.2359x over previous
//
#include <hip/hip_runtime.h>
#include <math.h>

#define NB 4
#define NN 4096
#define KSEL 204
#define QKSCALE 0.31622776601683794f

// workspace layout in floats
#define WS_Q 0
#define WS_KT (NB * NN * 10)       // 163840
#define WS_V (2 * NB * NN * 10)    // 327680
#define WS_LG (3 * NB * NN * 10)   // 491520  (+ NB*NN*2 = 32768)

#define SEQ_PER_BLOCK 16

__global__ __launch_bounds__(256) void featqkv_kernel(
    const float* __restrict__ x,
    const float* __restrict__ w2, const float* __restrict__ b2,
    const float* __restrict__ w3, const float* __restrict__ b3,
    const float* __restrict__ w4, const float* __restrict__ b4,
    const float* __restrict__ w5, const float* __restrict__ b5,
    const float* __restrict__ w6, const float* __restrict__ b6,
    const float* __restrict__ w7, const float* __restrict__ b7,
    const float* __restrict__ wq, const float* __restrict__ bq,
    const float* __restrict__ wk, const float* __restrict__ bk,
    const float* __restrict__ wv, const float* __restrict__ bv,
    float* __restrict__ q_out, float* __restrict__ kT_out, float* __restrict__ v_out)
{
    __shared__ float xs[SEQ_PER_BLOCK * 360];
    __shared__ float wconv[840];
    __shared__ float bconv[14];
    __shared__ float wqkv[420];
    __shared__ float bqkv[30];
    __shared__ float feats[SEQ_PER_BLOCK * 14];

    const int t = threadIdx.x;
    const int g0 = blockIdx.x * SEQ_PER_BLOCK;

    const float* xg = x + (size_t)g0 * 360;
    for (int i = t; i < SEQ_PER_BLOCK * 360; i += 256) xs[i] = xg[i];
    for (int i = t; i < 90; i += 256) wconv[i] = w2[i];
    for (int i = t; i < 135; i += 256) wconv[90 + i] = w3[i];
    for (int i = t; i < 180; i += 256) wconv[225 + i] = w4[i];
    for (int i = t; i < 150; i += 256) wconv[405 + i] = w5[i];
    for (int i = t; i < 180; i += 256) wconv[555 + i] = w6[i];
    for (int i = t; i < 105; i += 256) wconv[735 + i] = w7[i];
    if (t < 3) bconv[t] = b2[t];
    else if (t < 6) bconv[t] = b3[t - 3];
    else if (t < 9) bconv[t] = b4[t - 6];
    else if (t < 11) bconv[t] = b5[t - 9];
    else if (t < 13) bconv[t] = b6[t - 11];
    else if (t == 13) bconv[t] = b7[0];
    for (int i = t; i < 140; i += 256) wqkv[i] = wq[i];
    for (int i = t; i < 140; i += 256) wqkv[140 + i] = wk[i];
    for (int i = t; i < 140; i += 256) wqkv[280 + i] = wv[i];
    if (t < 10) bqkv[t] = bq[t];
    else if (t < 20) bqkv[t] = bk[t - 10];
    else if (t < 30) bqkv[t] = bv[t - 20];
    __syncthreads();

    const int seq = t >> 4;
    const int wkr = t & 15;

    if (wkr < 14) {
        const int ch = wkr;
        int h, fi, woff;
        if (ch < 3)       { h = 2; fi = ch;      woff = 0   + fi * 30; }
        else if (ch < 6)  { h = 3; fi = ch - 3;  woff = 90  + fi * 45; }
        else if (ch < 9)  { h = 4; fi = ch - 6;  woff = 225 + fi * 60; }
        else if (ch < 11) { h = 5; fi = ch - 9;  woff = 405 + fi * 75; }
        else if (ch < 13) { h = 6; fi = ch - 11; woff = 555 + fi * 90; }
        else              { h = 7; fi = 0;       woff = 735; }
        const int T = 24 - h + 1;

        float acc[23];
#pragma unroll
        for (int i2 = 0; i2 < 23; i2++) acc[i2] = 0.f;
        const float* xrow = &xs[seq * 360];
        for (int c = 0; c < 15; c++) {
            float xr[24];
#pragma unroll
            for (int u = 0; u < 24; u++) xr[u] = xrow[c * 24 + u];
#pragma unroll
            for (int j = 0; j < 7; j++) {
                if (j < h) {
                    float wv_ = wconv[woff + c * h + j];
#pragma unroll
                    for (int tt = 0; tt < 23; tt++) {
                        if (tt < T) acc[tt] = fmaf(xr[tt + j], wv_, acc[tt]);
                    }
                }
            }
        }
        float m = -1e30f;
#pragma unroll
        for (int tt = 0; tt < 23; tt++) {
            if (tt < T) m = fmaxf(m, acc[tt]);
        }
        feats[seq * 14 + ch] = fmaxf(m + bconv[ch], 0.f);
    }
    __syncthreads();

    const int g = g0 + seq;
    const int b_ = g >> 12;
    const int n_ = g & 4095;
    for (int o = wkr; o < 30; o += 16) {
        const int type = o / 10;
        const int comp = o % 10;
        const float* wrow = &wqkv[type * 140 + comp * 14];
        const float* frow = &feats[seq * 14];
        float a = bqkv[type * 10 + comp];
#pragma unroll
        for (int ii = 0; ii < 14; ii++) a = fmaf(frow[ii], wrow[ii], a);
        if (type == 0) q_out[(size_t)g * 10 + comp] = a;
        else if (type == 1) kT_out[((size_t)b_ * 10 + comp) * NN + n_] = a;
        else v_out[(size_t)g * 10 + comp] = a;
    }
}

__device__ __forceinline__ float dec_key(unsigned int k) {
    return (k & 0x80000000u) ? __uint_as_float(k ^ 0x80000000u)
                             : __uint_as_float(~k);
}

// 256 threads per block, one query row per block. Keys in LDS (no reg arrays).
__global__ __launch_bounds__(256, 8) void attn_kernel(
    const float* __restrict__ qbuf, const float* __restrict__ kTbuf,
    const float* __restrict__ vbuf,
    const float* __restrict__ w_attn, const float* __restrict__ b_attn,
    const float* __restrict__ w_mil, const float* __restrict__ b_mil,
    float* __restrict__ out_probs, float* __restrict__ logits)
{
    __shared__ unsigned int su[4096];         // monotonic score keys
    __shared__ unsigned int hist[256];
    __shared__ unsigned long long surv[256];
    __shared__ unsigned int wtot[4];
    __shared__ float fpart[4];
    __shared__ float ctxp[40];
    __shared__ float ctx_sh[10];
    __shared__ float attn_sh[14];
    __shared__ unsigned long long sh_pfx;
    __shared__ unsigned int sh_kept;
    __shared__ int sh_done;
    __shared__ unsigned int cnt;

    const int t = threadIdx.x;
    const int lane = t & 63;
    const int w = t >> 6;
    const int row = blockIdx.x;
    const int b_ = row >> 12;

    // ---- P1: scores -> monotonic keys in LDS ----
    float q[10];
#pragma unroll
    for (int c = 0; c < 10; c++) q[c] = qbuf[(size_t)row * 10 + c];
    const float* kTb = kTbuf + (size_t)b_ * 10 * NN;
#pragma unroll
    for (int i = 0; i < 16; i++) {
        const int j = i * 256 + t;
        float a = 0.f;
#pragma unroll
        for (int c = 0; c < 10; c++) a = fmaf(q[c], kTb[c * NN + j], a);
        unsigned int u = __float_as_uint(a);
        su[j] = (u & 0x80000000u) ? ~u : (u | 0x80000000u);
    }
    if (t == 0) { sh_done = 0; cnt = 0u; }
    __syncthreads();

    // ---- P2: radix select 204th-largest composite (key32<<16 | (4095-j)) ----
    unsigned long long pfx = 0ULL;
    unsigned int kept = KSEL;
#pragma unroll 1
    for (int pass = 0; pass < 6; pass++) {
        if (pass >= 4 && sh_done) break;   // score bits resolved uniquely
        const int shift = 40 - 8 * pass;
        hist[t] = 0u;
        __syncthreads();
#pragma unroll
        for (int i = 0; i < 16; i++) {
            const int j = i * 256 + t;
            unsigned long long key = (((unsigned long long)su[j]) << 16)
                                   | (unsigned long long)(4095 - j);
            if ((key >> (shift + 8)) == (pfx >> (shift + 8)))
                atomicAdd(&hist[(unsigned int)(key >> shift) & 255u], 1u);
        }
        __syncthreads();
        // suffix scan over 256 bins: wave-local shfl scan + cross-wave tails
        const unsigned int h = hist[t];
        unsigned int acc = h;
#pragma unroll
        for (int off = 1; off < 64; off <<= 1) {
            unsigned int o = __shfl_down(acc, off);
            if (lane + off < 64) acc += o;
        }
        if (lane == 0) wtot[w] = acc;      // wave total (suffix from lane 0)
        __syncthreads();
        unsigned int tail = 0u;
#pragma unroll
        for (int w2 = 1; w2 < 4; w2++) if (w2 > w) tail += wtot[w2];
        const unsigned int suf = acc + tail;       // suffix(t)
        const unsigned int sufnext = suf - h;      // suffix(t+1)
        if (suf >= kept && sufnext < kept) {       // unique pivot bin
            sh_pfx = pfx | (((unsigned long long)t) << shift);
            const unsigned int kn = kept - sufnext;
            sh_kept = kn;
            if (pass == 3) sh_done = (h == kn) ? 1 : 0;
        }
        __syncthreads();
        pfx = sh_pfx;
        kept = sh_kept;
        __syncthreads();
    }

    // ---- P3: compact survivors (exactly KSEL by construction) ----
    surv[t] = 0ULL;
    __syncthreads();
#pragma unroll
    for (int i = 0; i < 16; i++) {
        const int j = i * 256 + t;
        unsigned long long key = (((unsigned long long)su[j]) << 16)
                               | (unsigned long long)(4095 - j);
        if (key >= pfx) {
            unsigned int p = atomicAdd(&cnt, 1u);
            surv[p] = key;
        }
    }
    __syncthreads();

    // ---- P4: bitonic sort 256 keys descending ----
#pragma unroll 1
    for (int k2 = 2; k2 <= 256; k2 <<= 1) {
#pragma unroll 1
        for (int j2 = k2 >> 1; j2 > 0; j2 >>= 1) {
            const int ixj = t ^ j2;
            if (ixj > t) {
                unsigned long long a = surv[t], bk = surv[ixj];
                const bool desc = ((t & k2) == 0);
                if (desc ? (a < bk) : (a > bk)) { surv[t] = bk; surv[ixj] = a; }
            }
            __syncthreads();
        }
    }

    // ---- P5: softmax over selected scores (sorted order) ----
    const float smax = dec_key((unsigned int)(surv[0] >> 16)) * QKSCALE;
    float pv = 0.f;
    int jj = 0;
    if (t < KSEL) {
        const unsigned long long key = surv[t];
        jj = 4095 - (int)(key & 0xFFFFu);
        pv = expf(dec_key((unsigned int)(key >> 16)) * QKSCALE - smax);
    }
    float dsum = pv;
#pragma unroll
    for (int off = 32; off > 0; off >>= 1) dsum += __shfl_xor(dsum, off);
    if (lane == 0) fpart[w] = dsum;
    __syncthreads();
    const float inv = 1.f / (fpart[0] + fpart[1] + fpart[2] + fpart[3]);

    // ---- P6: probs out + ctx = sum p*v ----
    float ctx[10];
    const float pn = pv * inv;
    if (t < KSEL) {
        out_probs[(size_t)row * KSEL + t] = pn;
        const float* vr = vbuf + ((size_t)b_ * NN + (size_t)jj) * 10;
#pragma unroll
        for (int d = 0; d < 10; d++) ctx[d] = pn * vr[d];
    } else {
#pragma unroll
        for (int d = 0; d < 10; d++) ctx[d] = 0.f;
    }
#pragma unroll
    for (int d = 0; d < 10; d++) {
#pragma unroll
        for (int off = 32; off > 0; off >>= 1) ctx[d] += __shfl_xor(ctx[d], off);
    }
    if (lane == 0) {
#pragma unroll
        for (int d = 0; d < 10; d++) ctxp[w * 10 + d] = ctx[d];
    }
    __syncthreads();
    if (t < 10) ctx_sh[t] = ctxp[t] + ctxp[10 + t] + ctxp[20 + t] + ctxp[30 + t];
    __syncthreads();

    // ---- P7: attn projection + mil logits ----
    if (t < 14) {
        float a = b_attn[t];
#pragma unroll
        for (int d = 0; d < 10; d++) a = fmaf(ctx_sh[d], w_attn[t * 10 + d], a);
        attn_sh[t] = a;
    }
    __syncthreads();
    if (t < 2) {
        float lg = b_mil[t];
#pragma unroll
        for (int ii = 0; ii < 14; ii++) lg = fmaf(attn_sh[ii], w_mil[t * 14 + ii], lg);
        logits[(size_t)row * 2 + t] = lg;
    }
}

__global__ __launch_bounds__(256) void pool_kernel(
    const float* __restrict__ logits, float* __restrict__ out)
{
    __shared__ float red[256];
    const int t = threadIdx.x;
    const int bc = blockIdx.x;
    const int b_ = bc >> 1;
    const int c_ = bc & 1;
    float a = 0.f;
    for (int n2 = t; n2 < NN; n2 += 256)
        a += logits[((size_t)b_ * NN + n2) * 2 + c_];
    red[t] = a;
    __syncthreads();
    for (int off = 128; off > 0; off >>= 1) {
        if (t < off) red[t] += red[t + off];
        __syncthreads();
    }
    if (t == 0) out[bc] = red[0] * (1.f / 4096.f);
}

extern "C" void kernel_launch(void* const* d_in, const int* in_sizes, int n_in,
                              void* d_out, int out_size, void* d_ws, size_t ws_size,
                              hipStream_t stream) {
    const float* x  = (const float*)d_in[0];
    const float* w2 = (const float*)d_in[1];  const float* b2 = (const float*)d_in[2];
    const float* w3 = (const float*)d_in[3];  const float* b3 = (const float*)d_in[4];
    const float* w4 = (const float*)d_in[5];  const float* b4 = (const float*)d_in[6];
    const float* w5 = (const float*)d_in[7];  const float* b5 = (const float*)d_in[8];
    const float* w6 = (const float*)d_in[9];  const float* b6 = (const float*)d_in[10];
    const float* w7 = (const float*)d_in[11]; const float* b7 = (const float*)d_in[12];
    const float* wq = (const float*)d_in[13]; const float* bq = (const float*)d_in[14];
    const float* wk = (const float*)d_in[15]; const float* bk = (const float*)d_in[16];
    const float* wv = (const float*)d_in[17]; const float* bv = (const float*)d_in[18];
    const float* wat = (const float*)d_in[19]; const float* bat = (const float*)d_in[20];
    const float* wm = (const float*)d_in[21];  const float* bm = (const float*)d_in[22];

    float* ws = (float*)d_ws;
    float* qb = ws + WS_Q;
    float* kT = ws + WS_KT;
    float* vb = ws + WS_V;
    float* lg = ws + WS_LG;
    float* out = (float*)d_out;

    hipLaunchKernelGGL(featqkv_kernel, dim3(NB * NN / SEQ_PER_BLOCK), dim3(256), 0, stream,
                       x, w2, b2, w3, b3, w4, b4, w5, b5, w6, b6, w7, b7,
                       wq, bq, wk, bk, wv, bv, qb, kT, vb);
    hipLaunchKernelGGL(attn_kernel, dim3(NB * NN), dim3(256), 0, stream,
                       qb, kT, vb, wat, bat, wm, bm, out + 8, lg);
    hipLaunchKernelGGL(pool_kernel, dim3(8), dim3(256), 0, stream, lg, out);
}

// Round 4
// 261.654 us; speedup vs baseline: 6.6517x; 2.0556x over previous
//
#include <hip/hip_runtime.h>
#include <math.h>

#define NB 4
#define NN 4096
#define KSEL 204
#define NBINS 512
#define CANDN 256
#define QKSCALE 0.31622776601683794f

// workspace layout in floats
#define WS_Q 0
#define WS_KT (NB * NN * 10)       // 163840
#define WS_V (2 * NB * NN * 10)    // 327680
#define WS_LG (3 * NB * NN * 10)   // 491520  (+ NB*NN*2 = 32768)

#define SEQ_PER_BLOCK 16

__global__ __launch_bounds__(256) void featqkv_kernel(
    const float* __restrict__ x,
    const float* __restrict__ w2, const float* __restrict__ b2,
    const float* __restrict__ w3, const float* __restrict__ b3,
    const float* __restrict__ w4, const float* __restrict__ b4,
    const float* __restrict__ w5, const float* __restrict__ b5,
    const float* __restrict__ w6, const float* __restrict__ b6,
    const float* __restrict__ w7, const float* __restrict__ b7,
    const float* __restrict__ wq, const float* __restrict__ bq,
    const float* __restrict__ wk, const float* __restrict__ bk,
    const float* __restrict__ wv, const float* __restrict__ bv,
    float* __restrict__ q_out, float* __restrict__ kT_out, float* __restrict__ v_out)
{
    __shared__ float xs[SEQ_PER_BLOCK * 360];
    __shared__ float wconv[840];
    __shared__ float bconv[14];
    __shared__ float wqkv[420];
    __shared__ float bqkv[30];
    __shared__ float feats[SEQ_PER_BLOCK * 14];

    const int t = threadIdx.x;
    const int g0 = blockIdx.x * SEQ_PER_BLOCK;

    const float* xg = x + (size_t)g0 * 360;
    for (int i = t; i < SEQ_PER_BLOCK * 360; i += 256) xs[i] = xg[i];
    for (int i = t; i < 90; i += 256) wconv[i] = w2[i];
    for (int i = t; i < 135; i += 256) wconv[90 + i] = w3[i];
    for (int i = t; i < 180; i += 256) wconv[225 + i] = w4[i];
    for (int i = t; i < 150; i += 256) wconv[405 + i] = w5[i];
    for (int i = t; i < 180; i += 256) wconv[555 + i] = w6[i];
    for (int i = t; i < 105; i += 256) wconv[735 + i] = w7[i];
    if (t < 3) bconv[t] = b2[t];
    else if (t < 6) bconv[t] = b3[t - 3];
    else if (t < 9) bconv[t] = b4[t - 6];
    else if (t < 11) bconv[t] = b5[t - 9];
    else if (t < 13) bconv[t] = b6[t - 11];
    else if (t == 13) bconv[t] = b7[0];
    for (int i = t; i < 140; i += 256) wqkv[i] = wq[i];
    for (int i = t; i < 140; i += 256) wqkv[140 + i] = wk[i];
    for (int i = t; i < 140; i += 256) wqkv[280 + i] = wv[i];
    if (t < 10) bqkv[t] = bq[t];
    else if (t < 20) bqkv[t] = bk[t - 10];
    else if (t < 30) bqkv[t] = bv[t - 20];
    __syncthreads();

    const int seq = t >> 4;
    const int wkr = t & 15;

    if (wkr < 14) {
        const int ch = wkr;
        int h, fi, woff;
        if (ch < 3)       { h = 2; fi = ch;      woff = 0   + fi * 30; }
        else if (ch < 6)  { h = 3; fi = ch - 3;  woff = 90  + fi * 45; }
        else if (ch < 9)  { h = 4; fi = ch - 6;  woff = 225 + fi * 60; }
        else if (ch < 11) { h = 5; fi = ch - 9;  woff = 405 + fi * 75; }
        else if (ch < 13) { h = 6; fi = ch - 11; woff = 555 + fi * 90; }
        else              { h = 7; fi = 0;       woff = 735; }
        const int T = 24 - h + 1;

        float acc[23];
#pragma unroll
        for (int i2 = 0; i2 < 23; i2++) acc[i2] = 0.f;
        const float* xrow = &xs[seq * 360];
        for (int c = 0; c < 15; c++) {
            float xr[24];
#pragma unroll
            for (int u = 0; u < 24; u++) xr[u] = xrow[c * 24 + u];
#pragma unroll
            for (int j = 0; j < 7; j++) {
                if (j < h) {
                    float wv_ = wconv[woff + c * h + j];
#pragma unroll
                    for (int tt = 0; tt < 23; tt++) {
                        if (tt < T) acc[tt] = fmaf(xr[tt + j], wv_, acc[tt]);
                    }
                }
            }
        }
        float m = -1e30f;
#pragma unroll
        for (int tt = 0; tt < 23; tt++) {
            if (tt < T) m = fmaxf(m, acc[tt]);
        }
        feats[seq * 14 + ch] = fmaxf(m + bconv[ch], 0.f);
    }
    __syncthreads();

    const int g = g0 + seq;
    const int b_ = g >> 12;
    const int n_ = g & 4095;
    for (int o = wkr; o < 30; o += 16) {
        const int type = o / 10;
        const int comp = o % 10;
        const float* wrow = &wqkv[type * 140 + comp * 14];
        const float* frow = &feats[seq * 14];
        float a = bqkv[type * 10 + comp];
#pragma unroll
        for (int ii = 0; ii < 14; ii++) a = fmaf(frow[ii], wrow[ii], a);
        if (type == 0) q_out[(size_t)g * 10 + comp] = a;
        else if (type == 1) kT_out[((size_t)b_ * 10 + comp) * NN + n_] = a;
        else v_out[(size_t)g * 10 + comp] = a;
    }
}

__device__ __forceinline__ float dec_key(unsigned int k) {
    return (k & 0x80000000u) ? __uint_as_float(k ^ 0x80000000u)
                             : __uint_as_float(~k);
}
__device__ __forceinline__ unsigned int enc_key(float s) {
    unsigned int u = __float_as_uint(s);
    return (u & 0x80000000u) ? ~u : (u | 0x80000000u);
}

// 256 threads / 1 row per block. Scores in registers; linear-histogram rank.
__global__ __launch_bounds__(256, 6) void attn_kernel(
    const float* __restrict__ qbuf, const float* __restrict__ kTbuf,
    const float* __restrict__ vbuf,
    const float* __restrict__ w_attn, const float* __restrict__ b_attn,
    const float* __restrict__ w_mil, const float* __restrict__ b_mil,
    float* __restrict__ out_probs, float* __restrict__ logits)
{
    __shared__ unsigned int base_[NBINS];   // counts -> suffix-above (pristine)
    __shared__ unsigned int bc_[NBINS];     // mutable scatter counters
    __shared__ unsigned long long cand[CANDN];
    __shared__ float hpart[4], lpart[4], fpart[4];
    __shared__ unsigned int wtot[4];
    __shared__ float ctxp[40];
    __shared__ float ctx_sh[10];
    __shared__ float attn_sh[14];

    const int t = threadIdx.x;
    const int lane = t & 63;
    const int w = t >> 6;
    const int row = blockIdx.x;
    const int b_ = row >> 12;

    // ---- P1: scores (registers) + block min/max ----
    float q0, q1, q2, q3, q4, q5, q6, q7, q8, q9;
    {
        const float* qp = qbuf + (size_t)row * 10;
        q0 = qp[0]; q1 = qp[1]; q2 = qp[2]; q3 = qp[3]; q4 = qp[4];
        q5 = qp[5]; q6 = qp[6]; q7 = qp[7]; q8 = qp[8]; q9 = qp[9];
    }
    const float* kTb = kTbuf + (size_t)b_ * 10 * NN;
    float sc[16];
    float vhi = -1e30f, vlo = 1e30f;
#pragma unroll
    for (int i = 0; i < 4; i++) {
        float4 a0 = make_float4(0.f, 0.f, 0.f, 0.f);
#pragma unroll
        for (int c = 0; c < 10; c++) {
            const float qc = (c == 0) ? q0 : (c == 1) ? q1 : (c == 2) ? q2 : (c == 3) ? q3 :
                             (c == 4) ? q4 : (c == 5) ? q5 : (c == 6) ? q6 : (c == 7) ? q7 :
                             (c == 8) ? q8 : q9;
            const float4 kv = reinterpret_cast<const float4*>(kTb + c * NN)[i * 256 + t];
            a0.x = fmaf(qc, kv.x, a0.x);
            a0.y = fmaf(qc, kv.y, a0.y);
            a0.z = fmaf(qc, kv.z, a0.z);
            a0.w = fmaf(qc, kv.w, a0.w);
        }
        sc[i * 4 + 0] = a0.x; sc[i * 4 + 1] = a0.y;
        sc[i * 4 + 2] = a0.z; sc[i * 4 + 3] = a0.w;
        vhi = fmaxf(vhi, fmaxf(fmaxf(a0.x, a0.y), fmaxf(a0.z, a0.w)));
        vlo = fminf(vlo, fminf(fminf(a0.x, a0.y), fminf(a0.z, a0.w)));
    }
#pragma unroll
    for (int off = 32; off > 0; off >>= 1) {
        vhi = fmaxf(vhi, __shfl_xor(vhi, off));
        vlo = fminf(vlo, __shfl_xor(vlo, off));
    }
    if (lane == 0) { hpart[w] = vhi; lpart[w] = vlo; }
    // zero hist + cand under same barrier
    base_[2 * t] = 0u; base_[2 * t + 1] = 0u;
    cand[t] = 0ULL;
    __syncthreads();
    const float hi = fmaxf(fmaxf(hpart[0], hpart[1]), fmaxf(hpart[2], hpart[3]));
    const float lo = fminf(fminf(lpart[0], lpart[1]), fminf(lpart[2], lpart[3]));
    const bool degen = (hi <= lo);

    float pv = 0.f;
    int jj = 0, p = KSEL;
    bool selected = false;
    const float smax = hi * QKSCALE;

    if (!degen) {
        const float scale = (float)(NBINS - 1) / (hi - lo);

        // ---- P2: 512-bin linear histogram ----
#pragma unroll
        for (int i = 0; i < 16; i++) {
            const int bin = (int)fminf((sc[i] - lo) * scale, (float)(NBINS - 1));
            atomicAdd(&base_[bin], 1u);
        }
        __syncthreads();

        // ---- P3: suffix scan (2 bins/thread) -> base (pristine) + bc (mutable) ----
        {
            const unsigned int c0 = base_[2 * t];
            const unsigned int c1 = base_[2 * t + 1];
            const unsigned int T_ = c0 + c1;
            unsigned int acc = T_;
#pragma unroll
            for (int off = 1; off < 64; off <<= 1) {
                unsigned int o = __shfl_down(acc, off);
                if (lane + off < 64) acc += o;
            }
            if (lane == 0) wtot[w] = acc;
            __syncthreads();
            unsigned int tail = 0u;
#pragma unroll
            for (int w2 = 1; w2 < 4; w2++) if (w2 > w) tail += wtot[w2];
            const unsigned int A = (acc - T_) + tail;   // keys in bins > 2t+1
            base_[2 * t + 1] = A;
            base_[2 * t] = A + c1;
            bc_[2 * t + 1] = A;
            bc_[2 * t] = A + c1;
        }
        __syncthreads();

        // ---- P4: scatter candidate keys (bins whose base < KSEL) ----
#pragma unroll
        for (int i = 0; i < 16; i++) {
            const int bin = (int)fminf((sc[i] - lo) * scale, (float)(NBINS - 1));
            const unsigned int bs = base_[bin];
            if (bs < KSEL) {
                const unsigned int pos = atomicAdd(&bc_[bin], 1u);
                if (pos < CANDN) {
                    const int j = (i >> 2) * 1024 + t * 4 + (i & 3);
                    cand[pos] = (((unsigned long long)enc_key(sc[i])) << 16)
                              | (unsigned long long)(4095 - j);
                }
            }
        }
        __syncthreads();

        // ---- P5: within-bin rank -> exact sorted position ----
        const unsigned long long mine = cand[t];
        if (mine != 0ULL) {
            const float s = dec_key((unsigned int)(mine >> 16));
            const int bin = (int)fminf((s - lo) * scale, (float)(NBINS - 1));
            const unsigned int bs = base_[bin];
            unsigned int end = (bin < NBINS - 1) ? 0u : 0u; // placeholder
            end = (bin == NBINS - 1) ? bs + (4096u) : base_[bin + 1]; // not used
            // correct extent: bin's keys occupy [base[bin], base[bin-1])
            unsigned int e2 = (bin > 0) ? base_[bin - 1] : 4096u;
            if (e2 > CANDN) e2 = CANDN;
            unsigned int rank = 0;
            for (unsigned int s2 = bs; s2 < e2; s2++)
                rank += (cand[s2] > mine) ? 1u : 0u;
            const unsigned int pp = bs + rank;
            if (pp < KSEL) {
                selected = true;
                p = (int)pp;
                jj = 4095 - (int)(mine & 0xFFFFu);
                pv = expf(s * QKSCALE - smax);
            }
        }
    } else {
        // all scores equal: top-K = lowest indices, uniform softmax
        if (t < KSEL) {
            selected = true;
            p = t;
            jj = t;
            pv = 1.f;
        }
    }

    // ---- P6: softmax denom ----
    float dsum = pv;
#pragma unroll
    for (int off = 32; off > 0; off >>= 1) dsum += __shfl_xor(dsum, off);
    if (lane == 0) fpart[w] = dsum;
    __syncthreads();
    const float inv = 1.f / (fpart[0] + fpart[1] + fpart[2] + fpart[3]);

    // ---- P7: probs out + ctx ----
    float cx0 = 0.f, cx1 = 0.f, cx2 = 0.f, cx3 = 0.f, cx4 = 0.f;
    float cx5 = 0.f, cx6 = 0.f, cx7 = 0.f, cx8 = 0.f, cx9 = 0.f;
    if (selected) {
        const float pn = pv * inv;
        out_probs[(size_t)row * KSEL + p] = pn;
        const float* vr = vbuf + ((size_t)b_ * NN + (size_t)jj) * 10;
        const float2 v01 = reinterpret_cast<const float2*>(vr)[0];
        const float2 v23 = reinterpret_cast<const float2*>(vr)[1];
        const float2 v45 = reinterpret_cast<const float2*>(vr)[2];
        const float2 v67 = reinterpret_cast<const float2*>(vr)[3];
        const float2 v89 = reinterpret_cast<const float2*>(vr)[4];
        cx0 = pn * v01.x; cx1 = pn * v01.y;
        cx2 = pn * v23.x; cx3 = pn * v23.y;
        cx4 = pn * v45.x; cx5 = pn * v45.y;
        cx6 = pn * v67.x; cx7 = pn * v67.y;
        cx8 = pn * v89.x; cx9 = pn * v89.y;
    }
#pragma unroll
    for (int off = 32; off > 0; off >>= 1) {
        cx0 += __shfl_xor(cx0, off); cx1 += __shfl_xor(cx1, off);
        cx2 += __shfl_xor(cx2, off); cx3 += __shfl_xor(cx3, off);
        cx4 += __shfl_xor(cx4, off); cx5 += __shfl_xor(cx5, off);
        cx6 += __shfl_xor(cx6, off); cx7 += __shfl_xor(cx7, off);
        cx8 += __shfl_xor(cx8, off); cx9 += __shfl_xor(cx9, off);
    }
    if (lane == 0) {
        ctxp[w * 10 + 0] = cx0; ctxp[w * 10 + 1] = cx1; ctxp[w * 10 + 2] = cx2;
        ctxp[w * 10 + 3] = cx3; ctxp[w * 10 + 4] = cx4; ctxp[w * 10 + 5] = cx5;
        ctxp[w * 10 + 6] = cx6; ctxp[w * 10 + 7] = cx7; ctxp[w * 10 + 8] = cx8;
        ctxp[w * 10 + 9] = cx9;
    }
    __syncthreads();
    if (t < 10) ctx_sh[t] = ctxp[t] + ctxp[10 + t] + ctxp[20 + t] + ctxp[30 + t];
    __syncthreads();

    // ---- P8: attn projection + mil logits ----
    if (t < 14) {
        float a = b_attn[t];
#pragma unroll
        for (int d = 0; d < 10; d++) a = fmaf(ctx_sh[d], w_attn[t * 10 + d], a);
        attn_sh[t] = a;
    }
    __syncthreads();
    if (t < 2) {
        float lg = b_mil[t];
#pragma unroll
        for (int ii = 0; ii < 14; ii++) lg = fmaf(attn_sh[ii], w_mil[t * 14 + ii], lg);
        logits[(size_t)row * 2 + t] = lg;
    }
}

__global__ __launch_bounds__(256) void pool_kernel(
    const float* __restrict__ logits, float* __restrict__ out)
{
    __shared__ float red[256];
    const int t = threadIdx.x;
    const int bc = blockIdx.x;
    const int b_ = bc >> 1;
    const int c_ = bc & 1;
    float a = 0.f;
    for (int n2 = t; n2 < NN; n2 += 256)
        a += logits[((size_t)b_ * NN + n2) * 2 + c_];
    red[t] = a;
    __syncthreads();
    for (int off = 128; off > 0; off >>= 1) {
        if (t < off) red[t] += red[t + off];
        __syncthreads();
    }
    if (t == 0) out[bc] = red[0] * (1.f / 4096.f);
}

extern "C" void kernel_launch(void* const* d_in, const int* in_sizes, int n_in,
                              void* d_out, int out_size, void* d_ws, size_t ws_size,
                              hipStream_t stream) {
    const float* x  = (const float*)d_in[0];
    const float* w2 = (const float*)d_in[1];  const float* b2 = (const float*)d_in[2];
    const float* w3 = (const float*)d_in[3];  const float* b3 = (const float*)d_in[4];
    const float* w4 = (const float*)d_in[5];  const float* b4 = (const float*)d_in[6];
    const float* w5 = (const float*)d_in[7];  const float* b5 = (const float*)d_in[8];
    const float* w6 = (const float*)d_in[9];  const float* b6 = (const float*)d_in[10];
    const float* w7 = (const float*)d_in[11]; const float* b7 = (const float*)d_in[12];
    const float* wq = (const float*)d_in[13]; const float* bq = (const float*)d_in[14];
    const float* wk = (const float*)d_in[15]; const float* bk = (const float*)d_in[16];
    const float* wv = (const float*)d_in[17]; const float* bv = (const float*)d_in[18];
    const float* wat = (const float*)d_in[19]; const float* bat = (const float*)d_in[20];
    const float* wm = (const float*)d_in[21];  const float* bm = (const float*)d_in[22];

    float* ws = (float*)d_ws;
    float* qb = ws + WS_Q;
    float* kT = ws + WS_KT;
    float* vb = ws + WS_V;
    float* lg = ws + WS_LG;
    float* out = (float*)d_out;

    hipLaunchKernelGGL(featqkv_kernel, dim3(NB * NN / SEQ_PER_BLOCK), dim3(256), 0, stream,
                       x, w2, b2, w3, b3, w4, b4, w5, b5, w6, b6, w7, b7,
                       wq, bq, wk, bk, wv, bv, qb, kT, vb);
    hipLaunchKernelGGL(attn_kernel, dim3(NB * NN), dim3(256), 0, stream,
                       qb, kT, vb, wat, bat, wm, bm, out + 8, lg);
    hipLaunchKernelGGL(pool_kernel, dim3(8), dim3(256), 0, stream, lg, out);
}